// Round 1
// baseline (298.449 us; speedup 1.0000x reference)
//
#include <hip/hip_runtime.h>
#include <math.h>

#define NB 1024   // B
#define NA 512    // A
#define NC 64     // C
#define ND 10     // D
// LOG_TAIL = log(1024 - 512) = log(512)
#define LOG_TAIL 6.2383246250395077847f

// ---------------------------------------------------------------------------
// Kernel 1: per-row attention scalars.
// One block per batch row b. 256 threads; each thread owns raw indices
// {t, t+256, t+512, t+768} entirely in registers (no cross-thread raw use).
// Outputs: coef[b*512+a] = exp(attn+nattn - P), PQ[b] = {P, Q}.
// ---------------------------------------------------------------------------
__global__ __launch_bounds__(256) void k_attn(const float* __restrict__ a0,
                                              const float* __restrict__ a1,
                                              float* __restrict__ coef,
                                              float* __restrict__ PQ) {
  const int b = blockIdx.x;
  const int t = threadIdx.x;

  __shared__ float diff[16];
  __shared__ float sa1[16];
  __shared__ float redf[4];
  __shared__ double redd[8];

  if (t < ND) {
    float x0 = a0[b * ND + t];
    float x1 = a1[b * ND + t];
    diff[t] = x0 - x1;
    sa1[t] = x1;
  }
  __syncthreads();

  float base = 0.f;
#pragma unroll
  for (int d = 0; d < ND; ++d) base += sa1[d];

  // raw[i] = sum(a1) + sum_{d : bit(9-d) of i set} (a0-a1)[d]
  float raw[4];
#pragma unroll
  for (int r = 0; r < 4; ++r) {
    const int i = t + r * 256;
    float v = base;
#pragma unroll
    for (int d = 0; d < ND; ++d)
      if ((i >> (9 - d)) & 1) v += diff[d];
    raw[r] = v;
  }

  // y2 = LSE(raw[512..1023]) - LOG_TAIL   (raw[2],raw[3] per thread)
  float m = fmaxf(raw[2], raw[3]);
#pragma unroll
  for (int o = 32; o; o >>= 1) m = fmaxf(m, __shfl_xor(m, o));
  if ((t & 63) == 0) redf[t >> 6] = m;
  __syncthreads();
  m = fmaxf(fmaxf(redf[0], redf[1]), fmaxf(redf[2], redf[3]));
  __syncthreads();

  float se = __expf(raw[2] - m) + __expf(raw[3] - m);
#pragma unroll
  for (int o = 32; o; o >>= 1) se += __shfl_xor(se, o);
  if ((t & 63) == 0) redf[t >> 6] = se;
  __syncthreads();
  se = redf[0] + redf[1] + redf[2] + redf[3];
  __syncthreads();
  const float y2 = m + __logf(se) - LOG_TAIL;

  // attn[a] = logaddexp(raw[a], y2), a in {t, t+256}
  float at[2];
#pragma unroll
  for (int r = 0; r < 2; ++r) {
    float y1 = raw[r];
    float mx = fmaxf(y1, y2);
    float mn = fminf(y1, y2);
    at[r] = mx + log1pf(__expf(mn - mx));
  }

  // M = max_a attn
  float M = fmaxf(at[0], at[1]);
#pragma unroll
  for (int o = 32; o; o >>= 1) M = fmaxf(M, __shfl_xor(M, o));
  if ((t & 63) == 0) redf[t >> 6] = M;
  __syncthreads();
  M = fmaxf(fmaxf(redf[0], redf[1]), fmaxf(redf[2], redf[3]));
  __syncthreads();

  // T = sum exp(attn-M), Sq = sum exp(attn-M)^2  (fp64: nattn needs T - s[a]
  // without cancellation; reference's bidirectional cumlogsumexp is stable)
  float s[2];
  double T = 0.0, Sq = 0.0;
#pragma unroll
  for (int r = 0; r < 2; ++r) {
    s[r] = __expf(at[r] - M);
    T += (double)s[r];
    Sq += (double)s[r] * (double)s[r];
  }
#pragma unroll
  for (int o = 32; o; o >>= 1) {
    T += __shfl_xor(T, o);
    Sq += __shfl_xor(Sq, o);
  }
  if ((t & 63) == 0) { redd[t >> 6] = T; redd[4 + (t >> 6)] = Sq; }
  __syncthreads();
  T = redd[0] + redd[1] + redd[2] + redd[3];
  Sq = redd[4] + redd[5] + redd[6] + redd[7];
  __syncthreads();

  // w[a] = attn + nattn;  nattn = M + log(T - s[a])
  float w[2];
#pragma unroll
  for (int r = 0; r < 2; ++r) {
    float rem = (float)(T - (double)s[r]);
    w[r] = at[r] + M + __logf(rem);
  }

  // P = max_a w
  float P = fmaxf(w[0], w[1]);
#pragma unroll
  for (int o = 32; o; o >>= 1) P = fmaxf(P, __shfl_xor(P, o));
  if ((t & 63) == 0) redf[t >> 6] = P;
  __syncthreads();
  P = fmaxf(fmaxf(redf[0], redf[1]), fmaxf(redf[2], redf[3]));

  coef[b * NA + t] = __expf(w[0] - P);
  coef[b * NA + t + 256] = __expf(w[1] - P);
  if (t == 0) {
    PQ[b * 2] = P;
    PQ[b * 2 + 1] = 2.f * M + __logf((float)Sq);  // Q = log sum exp(2*attn)
  }
}

// ---------------------------------------------------------------------------
// Kernel 2: the 256 MB stream.
// One block per row b. Thread t: a-group ag = t>>4 (a = k*16+ag), c-quad
// cq = t&15 (c = 4*cq..4*cq+3). float4 index = k*256 + t -> each iteration
// the block reads a contiguous 4 KB from each of m0/m1 (perfect coalescing).
// acc[c] += coef[a] * exp(m[b,a,c]); reduce over ag via shfl(16,32) + LDS.
// r = P + log(acc + exp(v + Q - P)).
// ---------------------------------------------------------------------------
__global__ __launch_bounds__(256) void k_heavy(const float* __restrict__ m0,
                                               const float* __restrict__ m1,
                                               const float* __restrict__ v0,
                                               const float* __restrict__ v1,
                                               const float* __restrict__ coef,
                                               const float* __restrict__ PQ,
                                               float* __restrict__ out) {
  const int b = blockIdx.x;
  const int t = threadIdx.x;

  __shared__ float cf[NA];
  __shared__ float red[2][64][4];

  cf[t] = coef[b * NA + t];
  cf[t + 256] = coef[b * NA + t + 256];
  __syncthreads();

  const float4* p0 = (const float4*)(m0 + (size_t)b * (NA * NC));
  const float4* p1 = (const float4*)(m1 + (size_t)b * (NA * NC));
  const int ag = t >> 4;

  float acc0[4] = {0.f, 0.f, 0.f, 0.f};
  float acc1[4] = {0.f, 0.f, 0.f, 0.f};

#pragma unroll 4
  for (int k = 0; k < 32; ++k) {
    const float ca = cf[(k << 4) + ag];
    const float4 x0 = p0[(k << 8) + t];
    const float4 x1 = p1[(k << 8) + t];
    acc0[0] += ca * __expf(x0.x);
    acc0[1] += ca * __expf(x0.y);
    acc0[2] += ca * __expf(x0.z);
    acc0[3] += ca * __expf(x0.w);
    acc1[0] += ca * __expf(x1.x);
    acc1[1] += ca * __expf(x1.y);
    acc1[2] += ca * __expf(x1.z);
    acc1[3] += ca * __expf(x1.w);
  }

  // reduce over ag: lanes differing in bits 4,5 (intra-wave), then 4 waves.
#pragma unroll
  for (int o = 16; o < 64; o <<= 1) {
#pragma unroll
    for (int j = 0; j < 4; ++j) {
      acc0[j] += __shfl_xor(acc0[j], o);
      acc1[j] += __shfl_xor(acc1[j], o);
    }
  }
  if ((t & 63) < 16) {
    const int w = t >> 6;
#pragma unroll
    for (int j = 0; j < 4; ++j) {
      red[0][w * 16 + (t & 15)][j] = acc0[j];
      red[1][w * 16 + (t & 15)][j] = acc1[j];
    }
  }
  __syncthreads();

  if (t < 16) {
    const float P = PQ[b * 2];
    const float Q = PQ[b * 2 + 1];
    const float qp = Q - P;
#pragma unroll
    for (int j = 0; j < 4; ++j) {
      const int c = t * 4 + j;
      float s0 = red[0][t][j] + red[0][16 + t][j] + red[0][32 + t][j] + red[0][48 + t][j];
      float s1 = red[1][t][j] + red[1][16 + t][j] + red[1][32 + t][j] + red[1][48 + t][j];
      float e0 = __expf(v0[b * NC + c] + qp);
      float e1 = __expf(v1[b * NC + c] + qp);
      out[b * NC + c] = P + __logf(s0 + e0);
      out[NB * NC + b * NC + c] = P + __logf(s1 + e1);
    }
  }
}

extern "C" void kernel_launch(void* const* d_in, const int* in_sizes, int n_in,
                              void* d_out, int out_size, void* d_ws, size_t ws_size,
                              hipStream_t stream) {
  const float* m0 = (const float*)d_in[0];
  const float* m1 = (const float*)d_in[1];
  const float* a0 = (const float*)d_in[2];
  const float* a1 = (const float*)d_in[3];
  const float* v0 = (const float*)d_in[4];
  const float* v1 = (const float*)d_in[5];
  // b_0/b_1 (d_in[6..7]) are pure bit patterns of the index -> recomputed on the fly.

  float* coef = (float*)d_ws;          // NB*NA floats = 2 MB
  float* PQ = coef + NB * NA;          // 2*NB floats
  float* out = (float*)d_out;

  k_attn<<<NB, 256, 0, stream>>>(a0, a1, coef, PQ);
  k_heavy<<<NB, 256, 0, stream>>>(m0, m1, v0, v1, coef, PQ, out);
}

// Round 3
// 295.616 us; speedup vs baseline: 1.0096x; 1.0096x over previous
//
#include <hip/hip_runtime.h>
#include <math.h>

#define NB 1024   // B
#define NA 512    // A
#define NC 64     // C
#define ND 10     // D
// LOG_TAIL = log(1024 - 512) = log(512)
#define LOG_TAIL 6.2383246250395077847f

// ---------------------------------------------------------------------------
// Kernel 1: per-row attention scalars (unchanged from R1).
// One block per batch row b. Outputs: coef[b*512+a] = exp(attn+nattn - P),
// PQ[b] = {P, Q} with Q = log sum_a exp(2*attn).
// ---------------------------------------------------------------------------
__global__ __launch_bounds__(256) void k_attn(const float* __restrict__ a0,
                                              const float* __restrict__ a1,
                                              float* __restrict__ coef,
                                              float* __restrict__ PQ) {
  const int b = blockIdx.x;
  const int t = threadIdx.x;

  __shared__ float diff[16];
  __shared__ float sa1[16];
  __shared__ float redf[4];
  __shared__ double redd[8];

  if (t < ND) {
    float x0 = a0[b * ND + t];
    float x1 = a1[b * ND + t];
    diff[t] = x0 - x1;
    sa1[t] = x1;
  }
  __syncthreads();

  float base = 0.f;
#pragma unroll
  for (int d = 0; d < ND; ++d) base += sa1[d];

  // raw[i] = sum(a1) + sum_{d : bit(9-d) of i set} (a0-a1)[d]
  float raw[4];
#pragma unroll
  for (int r = 0; r < 4; ++r) {
    const int i = t + r * 256;
    float v = base;
#pragma unroll
    for (int d = 0; d < ND; ++d)
      if ((i >> (9 - d)) & 1) v += diff[d];
    raw[r] = v;
  }

  // y2 = LSE(raw[512..1023]) - LOG_TAIL
  float m = fmaxf(raw[2], raw[3]);
#pragma unroll
  for (int o = 32; o; o >>= 1) m = fmaxf(m, __shfl_xor(m, o));
  if ((t & 63) == 0) redf[t >> 6] = m;
  __syncthreads();
  m = fmaxf(fmaxf(redf[0], redf[1]), fmaxf(redf[2], redf[3]));
  __syncthreads();

  float se = __expf(raw[2] - m) + __expf(raw[3] - m);
#pragma unroll
  for (int o = 32; o; o >>= 1) se += __shfl_xor(se, o);
  if ((t & 63) == 0) redf[t >> 6] = se;
  __syncthreads();
  se = redf[0] + redf[1] + redf[2] + redf[3];
  __syncthreads();
  const float y2 = m + __logf(se) - LOG_TAIL;

  // attn[a] = logaddexp(raw[a], y2), a in {t, t+256}
  float at[2];
#pragma unroll
  for (int r = 0; r < 2; ++r) {
    float y1 = raw[r];
    float mx = fmaxf(y1, y2);
    float mn = fminf(y1, y2);
    at[r] = mx + log1pf(__expf(mn - mx));
  }

  // M = max_a attn
  float M = fmaxf(at[0], at[1]);
#pragma unroll
  for (int o = 32; o; o >>= 1) M = fmaxf(M, __shfl_xor(M, o));
  if ((t & 63) == 0) redf[t >> 6] = M;
  __syncthreads();
  M = fmaxf(fmaxf(redf[0], redf[1]), fmaxf(redf[2], redf[3]));
  __syncthreads();

  // T = sum exp(attn-M), Sq = sum exp(attn-M)^2 in fp64 (nattn = M+log(T-s[a])
  // must not cancel catastrophically)
  float s[2];
  double T = 0.0, Sq = 0.0;
#pragma unroll
  for (int r = 0; r < 2; ++r) {
    s[r] = __expf(at[r] - M);
    T += (double)s[r];
    Sq += (double)s[r] * (double)s[r];
  }
#pragma unroll
  for (int o = 32; o; o >>= 1) {
    T += __shfl_xor(T, o);
    Sq += __shfl_xor(Sq, o);
  }
  if ((t & 63) == 0) { redd[t >> 6] = T; redd[4 + (t >> 6)] = Sq; }
  __syncthreads();
  T = redd[0] + redd[1] + redd[2] + redd[3];
  Sq = redd[4] + redd[5] + redd[6] + redd[7];
  __syncthreads();

  float w[2];
#pragma unroll
  for (int r = 0; r < 2; ++r) {
    float rem = (float)(T - (double)s[r]);
    w[r] = at[r] + M + __logf(rem);
  }

  // P = max_a w
  float P = fmaxf(w[0], w[1]);
#pragma unroll
  for (int o = 32; o; o >>= 1) P = fmaxf(P, __shfl_xor(P, o));
  if ((t & 63) == 0) redf[t >> 6] = P;
  __syncthreads();
  P = fmaxf(fmaxf(redf[0], redf[1]), fmaxf(redf[2], redf[3]));

  coef[b * NA + t] = __expf(w[0] - P);
  coef[b * NA + t + 256] = __expf(w[1] - P);
  if (t == 0) {
    PQ[b * 2] = P;
    PQ[b * 2 + 1] = 2.f * M + __logf((float)Sq);  // Q = log sum exp(2*attn)
  }
}

// ---------------------------------------------------------------------------
// Kernel 2: the 256 MB stream, 2 blocks per row (2048 blocks = 8 blocks/CU
// = full 2048-thread occupancy). Block bh: row b = bh>>1, half h = bh&1
// (a-range h*256 .. h*256+255, i.e. k = 0..15 within the half).
// Thread t: a-group ag = t>>4, c-quad cq = t&15. float4 idx = k*256+t ->
// each iter the block reads contiguous 4 KB from each matrix half.
// Writes partial sums part[bh][mat][c]; epilogue moved to k_final.
// ---------------------------------------------------------------------------
__global__ __launch_bounds__(256) void k_heavy(const float* __restrict__ m0,
                                               const float* __restrict__ m1,
                                               const float* __restrict__ coef,
                                               float* __restrict__ part) {
  const int bh = blockIdx.x;
  const int b = bh >> 1;
  const int h = bh & 1;
  const int t = threadIdx.x;

  __shared__ float cf[256];
  __shared__ float red[2][64][4];

  cf[t] = coef[b * NA + h * 256 + t];
  __syncthreads();

  const float4* p0 = (const float4*)(m0) + (size_t)b * 8192 + h * 4096;
  const float4* p1 = (const float4*)(m1) + (size_t)b * 8192 + h * 4096;
  const int ag = t >> 4;

  float acc0[4] = {0.f, 0.f, 0.f, 0.f};
  float acc1[4] = {0.f, 0.f, 0.f, 0.f};

#pragma unroll 8
  for (int k = 0; k < 16; ++k) {
    const float ca = cf[(k << 4) + ag];
    const float4 x0 = p0[(k << 8) + t];
    const float4 x1 = p1[(k << 8) + t];
    acc0[0] += ca * __expf(x0.x);
    acc0[1] += ca * __expf(x0.y);
    acc0[2] += ca * __expf(x0.z);
    acc0[3] += ca * __expf(x0.w);
    acc1[0] += ca * __expf(x1.x);
    acc1[1] += ca * __expf(x1.y);
    acc1[2] += ca * __expf(x1.z);
    acc1[3] += ca * __expf(x1.w);
  }

  // reduce over ag: lanes differing in bits 4,5 (intra-wave), then 4 waves.
#pragma unroll
  for (int o = 16; o < 64; o <<= 1) {
#pragma unroll
    for (int j = 0; j < 4; ++j) {
      acc0[j] += __shfl_xor(acc0[j], o);
      acc1[j] += __shfl_xor(acc1[j], o);
    }
  }
  if ((t & 63) < 16) {
    const int w = t >> 6;
#pragma unroll
    for (int j = 0; j < 4; ++j) {
      red[0][w * 16 + (t & 15)][j] = acc0[j];
      red[1][w * 16 + (t & 15)][j] = acc1[j];
    }
  }
  __syncthreads();

  if (t < 16) {
#pragma unroll
    for (int j = 0; j < 4; ++j) {
      const int c = t * 4 + j;
      float s0 = red[0][t][j] + red[0][16 + t][j] + red[0][32 + t][j] + red[0][48 + t][j];
      float s1 = red[1][t][j] + red[1][16 + t][j] + red[1][32 + t][j] + red[1][48 + t][j];
      part[((size_t)bh * 2 + 0) * NC + c] = s0;
      part[((size_t)bh * 2 + 1) * NC + c] = s1;
    }
  }
}

// ---------------------------------------------------------------------------
// Kernel 3: combine the two half-row partials + epilogue.
// 1024 blocks x 128 threads: mat = t>>6, c = t&63.
// out = P + log(part_h0 + part_h1 + exp(v + Q - P)).
// ---------------------------------------------------------------------------
__global__ __launch_bounds__(128) void k_final(const float* __restrict__ part,
                                               const float* __restrict__ v0,
                                               const float* __restrict__ v1,
                                               const float* __restrict__ PQ,
                                               float* __restrict__ out) {
  const int b = blockIdx.x;
  const int t = threadIdx.x;
  const int mat = t >> 6;
  const int c = t & 63;

  const float P = PQ[b * 2];
  const float Q = PQ[b * 2 + 1];
  const float s = part[((size_t)(b * 2 + 0) * 2 + mat) * NC + c] +
                  part[((size_t)(b * 2 + 1) * 2 + mat) * NC + c];
  const float* v = mat ? v1 : v0;
  const float e = __expf(v[b * NC + c] + Q - P);
  out[(size_t)mat * NB * NC + b * NC + c] = P + __logf(s + e);
}

extern "C" void kernel_launch(void* const* d_in, const int* in_sizes, int n_in,
                              void* d_out, int out_size, void* d_ws, size_t ws_size,
                              hipStream_t stream) {
  const float* m0 = (const float*)d_in[0];
  const float* m1 = (const float*)d_in[1];
  const float* a0 = (const float*)d_in[2];
  const float* a1 = (const float*)d_in[3];
  const float* v0 = (const float*)d_in[4];
  const float* v1 = (const float*)d_in[5];
  // b_0/b_1 (d_in[6..7]) are pure bit patterns of the index -> recomputed.

  float* coef = (float*)d_ws;            // NB*NA floats        = 2 MB
  float* PQ = coef + NB * NA;            // 2*NB floats         = 8 KB
  float* part = PQ + 2 * NB;             // 2048*2*64 floats    = 1 MB
  float* out = (float*)d_out;

  k_attn<<<NB, 256, 0, stream>>>(a0, a1, coef, PQ);
  k_heavy<<<2 * NB, 256, 0, stream>>>(m0, m1, coef, part);
  k_final<<<NB, 128, 0, stream>>>(part, v0, v1, PQ, out);
}